// Round 1
// baseline (992.783 us; speedup 1.0000x reference)
//
#include <hip/hip_runtime.h>

#define B_SIZE 1024
#define T_LEN  256
#define D_IN   64
#define HC     32

__device__ __forceinline__ float frcp(float x){ return __builtin_amdgcn_rcpf(x); }
__device__ __forceinline__ float rfl(float x){
    return __uint_as_float(__builtin_amdgcn_readfirstlane(__float_as_uint(x)));
}
// tanh(x) = 1 - 2/(e^{2x}+1) ; graceful at +-inf
__device__ __forceinline__ float ftanh(float x){
    return 1.f - 2.f*frcp(__expf(2.f*x) + 1.f);
}
__device__ __forceinline__ float fsigmoid(float x){
    return frcp(1.f + __expf(-x));
}

// ---------------- conv0: x (B,T,64) -> t0 (B,32,T), relu(conv1d k3 pad1) ----------------
__global__ __launch_bounds__(256) void conv0_kernel(const float* __restrict__ x,
    const float* __restrict__ w0, const float* __restrict__ b0, float* __restrict__ out)
{
    __shared__ float xs[130*65];     // rows s0-1 .. s0+128, pad 65 vs bank conflicts
    __shared__ float wl[192*32];     // [r=d*3+k][c]
    const int tid = threadIdx.x;
    const int b  = blockIdx.x >> 1;
    const int s0 = (blockIdx.x & 1) * 128;

    for (int idx = tid; idx < 130*64; idx += 256){
        int r = idx >> 6, d = idx & 63;
        int s = s0 - 1 + r;
        float v = 0.f;
        if (s >= 0 && s < T_LEN) v = x[(size_t)b*(T_LEN*D_IN) + (size_t)s*D_IN + d];
        xs[r*65 + d] = v;
    }
    for (int idx = tid; idx < 192*32; idx += 256){
        int r = idx >> 5, c = idx & 31;
        wl[idx] = w0[c*192 + r];     // w0 layout (c,d,k): c*192 + d*3 + k
    }
    __syncthreads();

    const int c0 = (tid & 7) * 4;
    const int sl = (tid >> 3) * 4;
    float acc[4][4];
    #pragma unroll
    for (int ci = 0; ci < 4; ci++){
        float bb = b0[c0+ci];
        #pragma unroll
        for (int m = 0; m < 4; m++) acc[ci][m] = bb;
    }
    for (int d = 0; d < 64; d++){
        float xv[6];
        #pragma unroll
        for (int o = 0; o < 6; o++) xv[o] = xs[(sl+o)*65 + d];
        #pragma unroll
        for (int kk = 0; kk < 3; kk++){
            const float4 wv = *(const float4*)&wl[(d*3+kk)*32 + c0];
            float w4[4] = {wv.x, wv.y, wv.z, wv.w};
            #pragma unroll
            for (int ci = 0; ci < 4; ci++)
                #pragma unroll
                for (int m = 0; m < 4; m++)
                    acc[ci][m] += xv[m+kk]*w4[ci];
        }
    }
    #pragma unroll
    for (int ci = 0; ci < 4; ci++){
        float4 v;
        v.x = fmaxf(acc[ci][0], 0.f); v.y = fmaxf(acc[ci][1], 0.f);
        v.z = fmaxf(acc[ci][2], 0.f); v.w = fmaxf(acc[ci][3], 0.f);
        *(float4*)&out[(size_t)b*(HC*T_LEN) + (size_t)(c0+ci)*T_LEN + (s0+sl)] = v;
    }
}

// ------------- mid conv: in (B,32,T) -> out (B,32,T) or transposed (T,B,32) -------------
template<bool TOUT>
__global__ __launch_bounds__(256) void convm_kernel(const float* __restrict__ in,
    const float* __restrict__ w, const float* __restrict__ bias, float* __restrict__ out)
{
    __shared__ float xs[130*33];     // [row s'][cin]
    __shared__ float wl[96*32];      // [r=cin*3+k][c]
    const int tid = threadIdx.x;
    const int b  = blockIdx.x >> 1;
    const int s0 = (blockIdx.x & 1) * 128;

    for (int idx = tid; idx < 32*130; idx += 256){
        int ci = idx / 130; int r = idx - ci*130;
        int s = s0 - 1 + r;
        float v = 0.f;
        if (s >= 0 && s < T_LEN) v = in[(size_t)b*(HC*T_LEN) + (size_t)ci*T_LEN + s];
        xs[r*33 + ci] = v;
    }
    for (int idx = tid; idx < 96*32; idx += 256){
        int r = idx >> 5, c = idx & 31;
        wl[idx] = w[c*96 + r];       // w layout (c,cin,k)
    }
    __syncthreads();

    const int c0 = (tid & 7) * 4;
    const int sl = (tid >> 3) * 4;
    float acc[4][4];
    #pragma unroll
    for (int ci = 0; ci < 4; ci++){
        float bb = bias[c0+ci];
        #pragma unroll
        for (int m = 0; m < 4; m++) acc[ci][m] = bb;
    }
    for (int ci2 = 0; ci2 < 32; ci2++){
        float xv[6];
        #pragma unroll
        for (int o = 0; o < 6; o++) xv[o] = xs[(sl+o)*33 + ci2];
        #pragma unroll
        for (int kk = 0; kk < 3; kk++){
            const float4 wv = *(const float4*)&wl[(ci2*3+kk)*32 + c0];
            float w4[4] = {wv.x, wv.y, wv.z, wv.w};
            #pragma unroll
            for (int ci = 0; ci < 4; ci++)
                #pragma unroll
                for (int m = 0; m < 4; m++)
                    acc[ci][m] += xv[m+kk]*w4[ci];
        }
    }
    if (!TOUT){
        #pragma unroll
        for (int ci = 0; ci < 4; ci++){
            float4 v;
            v.x = fmaxf(acc[ci][0], 0.f); v.y = fmaxf(acc[ci][1], 0.f);
            v.z = fmaxf(acc[ci][2], 0.f); v.w = fmaxf(acc[ci][3], 0.f);
            *(float4*)&out[(size_t)b*(HC*T_LEN) + (size_t)(c0+ci)*T_LEN + (s0+sl)] = v;
        }
    } else {
        #pragma unroll
        for (int m = 0; m < 4; m++){
            int s = s0 + sl + m;
            float4 v;
            v.x = fmaxf(acc[0][m], 0.f); v.y = fmaxf(acc[1][m], 0.f);
            v.z = fmaxf(acc[2][m], 0.f); v.w = fmaxf(acc[3][m], 0.f);
            *(float4*)&out[(size_t)s*(B_SIZE*HC) + (size_t)b*HC + c0] = v;
        }
    }
}

// ---------------- scan: one wave per batch element, zero inter-wave sync ----------------
__global__ __launch_bounds__(256, 1) void scan_kernel(
    const float* __restrict__ tS,
    const float* __restrict__ Wih, const float* __restrict__ Whh,
    const float* __restrict__ bih, const float* __restrict__ bhh,
    const float* __restrict__ qw,  const float* __restrict__ Wfc,
    const float* __restrict__ bfc, const float* __restrict__ Wout,
    const float* __restrict__ bout, float* __restrict__ out)
{
    const int lane = threadIdx.x & 63;
    const int wv   = threadIdx.x >> 6;
    const int b    = __builtin_amdgcn_readfirstlane(blockIdx.x * 4 + wv);
    const int r1 = lane, r2 = lane + 64;       // gate rows: [i f | g o]
    const int k  = lane & 31;

    // register-resident gate weight rows (128 VGPRs)
    float wA[32], wB[32], uA[32], uB[32];
    #pragma unroll
    for (int j4 = 0; j4 < 8; j4++){
        float4 a = ((const float4*)Wih)[r1*8 + j4];
        float4 c_ = ((const float4*)Wih)[r2*8 + j4];
        float4 d_ = ((const float4*)Whh)[r1*8 + j4];
        float4 e  = ((const float4*)Whh)[r2*8 + j4];
        wA[j4*4+0]=a.x; wA[j4*4+1]=a.y; wA[j4*4+2]=a.z; wA[j4*4+3]=a.w;
        wB[j4*4+0]=c_.x; wB[j4*4+1]=c_.y; wB[j4*4+2]=c_.z; wB[j4*4+3]=c_.w;
        uA[j4*4+0]=d_.x; uA[j4*4+1]=d_.y; uA[j4*4+2]=d_.z; uA[j4*4+3]=d_.w;
        uB[j4*4+0]=e.x; uB[j4*4+1]=e.y; uB[j4*4+2]=e.z; uB[j4*4+3]=e.w;
    }
    const float bias1 = bih[r1] + bhh[r1];
    const float bias2 = bih[r2] + bhh[r2];

    float wfcr[6];
    #pragma unroll
    for (int j = 0; j < 6; j++) wfcr[j] = Wfc[k*6 + j];
    const float bfcl  = bfc[k];
    const float woutl = (lane < 32) ? Wout[k] : 0.f;
    const float boutv = bout[0];

    // fixed layer RY angles (wave-uniform -> SGPRs)
    float lc[18], ls[18];
    #pragma unroll
    for (int t = 0; t < 18; t++){
        float a = 0.5f * qw[t];
        lc[t] = rfl(__cosf(a));
        ls[t] = rfl(__sinf(a));
    }

    float h = 0.f, c = 0.f;
    const float* xbase = tS + (size_t)b*HC;

    // prefetch step 0
    float4 xf[8];
    #pragma unroll
    for (int j4 = 0; j4 < 8; j4++) xf[j4] = ((const float4*)xbase)[j4];

    #pragma clang loop unroll(disable)
    for (int s = 0; s < T_LEN; s++){
        float xt[32];
        #pragma unroll
        for (int j4 = 0; j4 < 8; j4++){
            xt[j4*4+0]=xf[j4].x; xt[j4*4+1]=xf[j4].y; xt[j4*4+2]=xf[j4].z; xt[j4*4+3]=xf[j4].w;
        }
        { // prefetch next step
            int s2 = (s + 1 < T_LEN) ? s + 1 : s;
            const float4* np_ = (const float4*)(xbase + (size_t)s2*(B_SIZE*HC));
            #pragma unroll
            for (int j4 = 0; j4 < 8; j4++) xf[j4] = np_[j4];
        }

        // ---- LSTM gates ----
        float acc1 = bias1, acc2 = bias2;
        #pragma unroll
        for (int j = 0; j < 32; j++){ acc1 += xt[j]*wA[j]; acc2 += xt[j]*wB[j]; }
        #pragma unroll
        for (int j = 0; j < 32; j++){
            float hj = __shfl(h, j, 64);
            acc1 += hj*uA[j]; acc2 += hj*uB[j];
        }
        float sigA = fsigmoid(acc1);                 // low: sig(i), high: sig(f)
        float argB = (lane < 32) ? acc2 : 0.5f*acc2; // low: tanh(g), high: sig(o)=0.5+0.5*tanh(x/2)
        float tt   = ftanh(argB);
        float actB = (lane < 32) ? tt : (0.5f + 0.5f*tt);
        float fsig = __shfl_xor(sigA, 32, 64);
        c = fsig*c + sigA*actB;
        float osig = __shfl_xor(actB, 32, 64);
        float hn = osig * ftanh(c);

        // ---- logistic + henon ----
        hn = 3.99f * hn * (1.f - hn);
        float x0 = __shfl(hn, 0, 64);
        float y0 = __shfl(hn, 1, 64);
        float xnv = 1.f - 1.4f*x0*x0 + y0;
        float ynv = 0.3f * x0;
        hn = (lane == 0) ? xnv : ((lane == 1) ? ynv : hn);

        // ---- quantum circuit: product-state init ----
        float ca[6], sa[6];
        #pragma unroll
        for (int j = 0; j < 6; j++){
            float a = 0.5f * __shfl(hn, j, 64);
            ca[j] = __cosf(a); sa[j] = __sinf(a);
        }
        float q0r[6], q0i[6], q1r[6], q1i[6];
        #pragma unroll
        for (int i = 0; i < 6; i++){
            const int i1 = (i+1)%6, i2 = (i+2)%6;
            float cx=ca[i], sx=sa[i], cy=ca[i1], sy=sa[i1], cz=ca[i2], sz=sa[i2];
            float w0r = cy*cx, w0i = sy*sx;       // RY*RX|0>
            float w1r = sy*cx, w1i = -cy*sx;
            q0r[i] = cz*w0r + sz*w0i; q0i[i] = cz*w0i - sz*w0r;   // * e^{-i az}
            q1r[i] = cz*w1r - sz*w1i; q1i[i] = cz*w1i + sz*w1r;   // * e^{+i az}
        }
        // amplitude = product over qubits; qubit i bit = (lane >> (5-i)) & 1
        float ar, ai;
        {
            int bt = (lane >> 5) & 1;
            ar = bt ? q1r[0] : q0r[0];
            ai = bt ? q1i[0] : q0i[0];
            #pragma unroll
            for (int i = 1; i < 6; i++){
                int bb2 = (lane >> (5-i)) & 1;
                float br = bb2 ? q1r[i] : q0r[i];
                float bi = bb2 ? q1i[i] : q0i[i];
                float nr = ar*br - ai*bi;
                float ni = ar*bi + ai*br;
                ar = nr; ai = ni;
            }
        }
        // ---- entangling layers (fixed angles) ----
        #pragma unroll
        for (int l = 0; l < 3; l++){
            #pragma unroll
            for (int q = 0; q < 6; q++){
                float cg = lc[l*6+q], sg_ = ls[l*6+q];
                int m = 32 >> q;
                float br = __shfl_xor(ar, m, 64);
                float bi = __shfl_xor(ai, m, 64);
                float sgn = (lane & m) ? sg_ : -sg_;
                ar = cg*ar + sgn*br;
                ai = cg*ai + sgn*bi;
            }
            #pragma unroll
            for (int q = 0; q < 6; q++){
                int mc = 32 >> q, mt = 32 >> ((q+1)%6);
                float br = __shfl_xor(ar, mt, 64);
                float bi = __shfl_xor(ai, mt, 64);
                if (lane & mc){ ar = br; ai = bi; }
            }
        }
        // ---- expvals: shared-prefix signed butterflies ----
        float p = ar*ar + ai*ai;
        float ev[6];
        float cur = p;
        #pragma unroll
        for (int j = 0; j < 6; j++){              // bitpos j <-> qubit 5-j
            float pj = __shfl_xor(cur, 1 << j, 64);
            float d = cur - pj;
            d = (lane & (1 << j)) ? -d : d;
            #pragma unroll
            for (int kk = j+1; kk < 6; kk++) d += __shfl_xor(d, 1 << kk, 64);
            ev[5-j] = d;
            cur += pj;
        }
        // ---- h update ----
        float upd = bfcl;
        #pragma unroll
        for (int j = 0; j < 6; j++) upd += ev[j]*wfcr[j];
        h = hn + upd;
    }

    // ---- output: sigmoid(h . Wout + bout) ----
    float pv = (lane < 32) ? h*woutl : 0.f;
    #pragma unroll
    for (int off = 32; off; off >>= 1) pv += __shfl_xor(pv, off, 64);
    if (lane == 0) out[b] = fsigmoid(pv + boutv);
}

extern "C" void kernel_launch(void* const* d_in, const int* in_sizes, int n_in,
                              void* d_out, int out_size, void* d_ws, size_t ws_size,
                              hipStream_t stream)
{
    const float* x    = (const float*)d_in[0];
    const float* w0   = (const float*)d_in[1];
    const float* b0   = (const float*)d_in[2];
    const float* w1   = (const float*)d_in[3];
    const float* b1   = (const float*)d_in[4];
    const float* w2   = (const float*)d_in[5];
    const float* b2   = (const float*)d_in[6];
    const float* Wih  = (const float*)d_in[7];
    const float* Whh  = (const float*)d_in[8];
    const float* bih  = (const float*)d_in[9];
    const float* bhh  = (const float*)d_in[10];
    const float* qw   = (const float*)d_in[11];
    const float* Wfc  = (const float*)d_in[12];
    const float* bfc  = (const float*)d_in[13];
    const float* Wout = (const float*)d_in[14];
    const float* bout = (const float*)d_in[15];
    float* out = (float*)d_out;

    float* t0 = (float*)d_ws;                              // (B,32,T) 32 MB
    float* t1 = t0 + (size_t)B_SIZE*HC*T_LEN;              // (B,32,T) 32 MB
    float* tS = t0;                                        // (T,B,32) reuses t0 region

    conv0_kernel<<<2048, 256, 0, stream>>>(x, w0, b0, t0);
    convm_kernel<false><<<2048, 256, 0, stream>>>(t0, w1, b1, t1);
    convm_kernel<true ><<<2048, 256, 0, stream>>>(t1, w2, b2, tS);
    scan_kernel<<<256, 256, 0, stream>>>(tS, Wih, Whh, bih, bhh, qw, Wfc, bfc, Wout, bout, out);
}

// Round 3
// 777.770 us; speedup vs baseline: 1.2764x; 1.2764x over previous
//
#include <hip/hip_runtime.h>

#define B_SIZE 1024
#define T_LEN  256
#define D_IN   64
#define HC     32

__device__ __forceinline__ float frcp(float x){ return __builtin_amdgcn_rcpf(x); }
__device__ __forceinline__ float rfl(float x){
    return __uint_as_float(__builtin_amdgcn_readfirstlane(__float_as_uint(x)));
}
__device__ __forceinline__ float rdlane(float x, int l){
    return __int_as_float(__builtin_amdgcn_readlane(__float_as_int(x), l));
}
// tanh(x) = 1 - 2/(e^{2x}+1)
__device__ __forceinline__ float ftanh(float x){
    return 1.f - 2.f*frcp(__expf(2.f*x) + 1.f);
}
__device__ __forceinline__ float fsigmoid(float x){
    return frcp(1.f + __expf(-x));
}

template<int CTRL>
__device__ __forceinline__ int dppmov(int x){
    return __builtin_amdgcn_update_dpp(x, x, CTRL, 0xF, 0xF, false);
}

// value of lane (lane ^ M) — proven primitives only:
//  M with bit32: ds_bpermute full-wave xor (one op, R1-proven via __shfl)
//  M in {1,2,3}: quad_perm DPP ; M==8: row_ror:8 DPP
//  other M<=31 : ds_swizzle BitMode (xor<<10)|0x1F (ISA-doc butterfly idiom)
template<int M>
__device__ __forceinline__ float xshuf(float xf, unsigned lane){
    if constexpr (M == 0){
        return xf;
    } else if constexpr (M & 32){
        return __shfl(xf, (int)(lane ^ (unsigned)M), 64);
    } else if constexpr ((M & ~3) == 0){
        constexpr int ctrl = (M == 1) ? 0xB1 : (M == 2) ? 0x4E : 0x1B;
        return __int_as_float(dppmov<ctrl>(__float_as_int(xf)));
    } else if constexpr (M == 8){
        return __int_as_float(dppmov<0x128>(__float_as_int(xf)));
    } else {
        return __int_as_float(__builtin_amdgcn_ds_swizzle(__float_as_int(xf), (M << 10) | 0x1F));
    }
}

// ---- compile-time GF(2) tracking of the CNOT-ring basis relabeling ----
// qubit i <-> lane bit (5-i). Ring CNOT(q,(q+1)%6), q=0..5, permutes basis
// indices linearly: state_after[b] = state_before[Pi b]. We never permute
// amplitudes; with C_l = Pi^l, layer-l RY(q) in stored space uses exchange
// mask col_q(Pi^l) and sign row row_q(Pi^-l); expvals read WHT at rows of
// Pi^-3. (m tracks Pi^-l = B^l, n tracks Pi^l; verified by hand, 2-qubit.)
struct QMasks { int M[3][6]; int S[3][6]; int R[6]; };
constexpr QMasks qmasks(){
    QMasks qm{};
    unsigned m[6], n[6];
    for (int i = 0; i < 6; i++){ m[i] = 1u << i; n[i] = 1u << i; }
    for (int l = 0; l < 3; l++){
        for (int q = 0; q < 6; q++){
            // sign mask: lanemask(row_q(Pi^-l)) from m
            unsigned u = m[q], r = 0;
            for (int i = 0; i < 6; i++) if ((u >> i) & 1u) r |= (32u >> i);
            qm.S[l][q] = (int)r;
            // exchange mask: lanemask(col_q(Pi^l)) from n
            unsigned u2 = 0;
            for (int i = 0; i < 6; i++) u2 |= ((n[i] >> q) & 1u) << i;
            unsigned r2 = 0;
            for (int i = 0; i < 6; i++) if ((u2 >> i) & 1u) r2 |= (32u >> i);
            qm.M[l][q] = (int)r2;
        }
        // m <- B * m  (B = Pi^-1, basis-state forward map)
        for (int q = 0; q < 6; q++) m[(q + 1) % 6] ^= m[q];
        // n <- Pi * n
        n[0] ^= n[5];
        for (int q = 4; q >= 0; q--) n[q + 1] ^= n[q];
    }
    for (int i = 0; i < 6; i++){
        unsigned u = m[i], r = 0;
        for (int j = 0; j < 6; j++) if ((u >> j) & 1u) r |= (32u >> j);
        qm.R[i] = (int)r;
    }
    return qm;
}
constexpr QMasks QM = qmasks();

// ---------------- conv0: x (B,T,64) -> t0 (B,32,T), relu(conv1d k3 pad1) ---------------
__global__ __launch_bounds__(64) void conv0_kernel(const float* __restrict__ x,
    const float* __restrict__ w0, const float* __restrict__ b0, float* __restrict__ out)
{
    __shared__ float xs[66*65];
    const int tid = threadIdx.x;
    const int b  = blockIdx.x >> 2;
    const int s0 = (blockIdx.x & 3) * 64;

    for (int idx = tid; idx < 66*64; idx += 64){
        int r = idx >> 6, d = idx & 63;
        int s = s0 - 1 + r;
        float v = (s >= 0 && s < T_LEN) ? x[(size_t)b*(T_LEN*D_IN) + (size_t)s*D_IN + d] : 0.f;
        xs[r*65 + d] = v;
    }
    __syncthreads();

    float acc[32];
    #pragma unroll
    for (int c = 0; c < 32; c++) acc[c] = b0[c];

    for (int d = 0; d < 64; d++){
        float xv0 = xs[(tid+0)*65 + d];
        float xv1 = xs[(tid+1)*65 + d];
        float xv2 = xs[(tid+2)*65 + d];
        #pragma unroll
        for (int c = 0; c < 32; c++){
            const float* wr = &w0[c*192 + d*3];   // uniform -> s_load
            acc[c] += xv0*wr[0] + xv1*wr[1] + xv2*wr[2];
        }
    }
    const int s = s0 + tid;
    #pragma unroll
    for (int c = 0; c < 32; c++)
        out[(size_t)b*(HC*T_LEN) + (size_t)c*T_LEN + s] = fmaxf(acc[c], 0.f);
}

// ------------- mid conv: in (B,32,T) -> out (B,32,T) or transposed (T,B,32) ------------
template<bool TOUT>
__global__ __launch_bounds__(64) void convm_kernel(const float* __restrict__ in,
    const float* __restrict__ w, const float* __restrict__ bias, float* __restrict__ out)
{
    __shared__ float xs[66*33];
    const int tid = threadIdx.x;
    const int b  = blockIdx.x >> 2;
    const int s0 = (blockIdx.x & 3) * 64;

    for (int idx = tid; idx < 32*66; idx += 64){
        int ci = idx / 66; int r = idx - ci*66;
        int s = s0 - 1 + r;
        float v = (s >= 0 && s < T_LEN) ? in[(size_t)b*(HC*T_LEN) + (size_t)ci*T_LEN + s] : 0.f;
        xs[r*33 + ci] = v;
    }
    __syncthreads();

    float acc[32];
    #pragma unroll
    for (int c = 0; c < 32; c++) acc[c] = bias[c];

    for (int ci = 0; ci < 32; ci++){
        float xv0 = xs[(tid+0)*33 + ci];
        float xv1 = xs[(tid+1)*33 + ci];
        float xv2 = xs[(tid+2)*33 + ci];
        #pragma unroll
        for (int c = 0; c < 32; c++){
            const float* wr = &w[c*96 + ci*3];    // uniform -> s_load
            acc[c] += xv0*wr[0] + xv1*wr[1] + xv2*wr[2];
        }
    }
    const int s = s0 + tid;
    if (!TOUT){
        #pragma unroll
        for (int c = 0; c < 32; c++)
            out[(size_t)b*(HC*T_LEN) + (size_t)c*T_LEN + s] = fmaxf(acc[c], 0.f);
    } else {
        #pragma unroll
        for (int c4 = 0; c4 < 8; c4++){
            float4 v;
            v.x = fmaxf(acc[c4*4+0], 0.f); v.y = fmaxf(acc[c4*4+1], 0.f);
            v.z = fmaxf(acc[c4*4+2], 0.f); v.w = fmaxf(acc[c4*4+3], 0.f);
            *(float4*)&out[(size_t)s*(B_SIZE*HC) + (size_t)b*HC + c4*4] = v;
        }
    }
}

// ---------------- scan: one wave per batch element ----------------
__global__ __launch_bounds__(256, 1) void scan_kernel(
    const float* __restrict__ tS,
    const float* __restrict__ Wih, const float* __restrict__ Whh,
    const float* __restrict__ bih, const float* __restrict__ bhh,
    const float* __restrict__ qw,  const float* __restrict__ Wfc,
    const float* __restrict__ bfc, const float* __restrict__ Wout,
    const float* __restrict__ bout, float* __restrict__ out)
{
    const unsigned lane = threadIdx.x & 63u;
    const int wv   = threadIdx.x >> 6;
    const int b    = __builtin_amdgcn_readfirstlane(blockIdx.x * 4 + wv);
    const int r1 = lane, r2 = lane + 64;       // gate rows: [i f | g o]
    const int k  = lane & 31;

    // register-resident gate weight rows (128 VGPRs)
    float wA[32], wB[32], uA[32], uB[32];
    #pragma unroll
    for (int j4 = 0; j4 < 8; j4++){
        float4 a  = ((const float4*)Wih)[r1*8 + j4];
        float4 c_ = ((const float4*)Wih)[r2*8 + j4];
        float4 d_ = ((const float4*)Whh)[r1*8 + j4];
        float4 e  = ((const float4*)Whh)[r2*8 + j4];
        wA[j4*4+0]=a.x;  wA[j4*4+1]=a.y;  wA[j4*4+2]=a.z;  wA[j4*4+3]=a.w;
        wB[j4*4+0]=c_.x; wB[j4*4+1]=c_.y; wB[j4*4+2]=c_.z; wB[j4*4+3]=c_.w;
        uA[j4*4+0]=d_.x; uA[j4*4+1]=d_.y; uA[j4*4+2]=d_.z; uA[j4*4+3]=d_.w;
        uB[j4*4+0]=e.x;  uB[j4*4+1]=e.y;  uB[j4*4+2]=e.z;  uB[j4*4+3]=e.w;
    }
    const float bias1 = bih[r1] + bhh[r1];
    const float bias2 = bih[r2] + bhh[r2];

    float wfcr[6];
    #pragma unroll
    for (int j = 0; j < 6; j++) wfcr[j] = Wfc[k*6 + j];
    const float bfcl  = bfc[k];
    const float woutl = (lane < 32) ? Wout[k] : 0.f;
    const float boutv = bout[0];

    // fixed-layer RY constants: uniform cos (SGPR) + per-lane parity-signed sin
    float cgv[18], ssin[18];
    #pragma unroll
    for (int g = 0; g < 18; g++){
        int l = g / 6, q = g % 6;
        float a = 0.5f * qw[g];
        float cv = __cosf(a), sv = __sinf(a);
        cgv[g] = rfl(cv);
        unsigned sm = (unsigned)QM.S[l][q];
        ssin[g] = (__builtin_popcount(sm & lane) & 1) ? sv : -sv;
    }
    // WHT stage signs and product-state qubit selectors
    float wsgn[6];
    #pragma unroll
    for (int j = 0; j < 6; j++) wsgn[j] = (lane & (1u << j)) ? -1.f : 1.f;
    const bool qb0 = (lane & 32u) != 0, qb1 = (lane & 16u) != 0, qb2 = (lane & 8u) != 0;
    const bool qb3 = (lane & 4u) != 0,  qb4 = (lane & 2u) != 0,  qb5 = (lane & 1u) != 0;

    float h = 0.f, c = 0.f;
    const float* xbase = tS + (size_t)b * HC;

    float4 xf[8];
    #pragma unroll
    for (int j4 = 0; j4 < 8; j4++) xf[j4] = ((const float4*)xbase)[j4];

    #pragma clang loop unroll(disable)
    for (int s = 0; s < T_LEN; s++){
        float xt[32];
        #pragma unroll
        for (int j4 = 0; j4 < 8; j4++){
            xt[j4*4+0]=xf[j4].x; xt[j4*4+1]=xf[j4].y; xt[j4*4+2]=xf[j4].z; xt[j4*4+3]=xf[j4].w;
        }
        { // prefetch next step
            int s2 = (s + 1 < T_LEN) ? s + 1 : s;
            const float4* np_ = (const float4*)(xbase + (size_t)s2*(B_SIZE*HC));
            #pragma unroll
            for (int j4 = 0; j4 < 8; j4++) xf[j4] = np_[j4];
        }

        // ---- LSTM gates ----
        float a1a = bias1, a1b = 0.f, a2a = bias2, a2b = 0.f;
        #pragma unroll
        for (int j = 0; j < 32; j += 2){
            a1a += xt[j]*wA[j];     a1b += xt[j+1]*wA[j+1];
            a2a += xt[j]*wB[j];     a2b += xt[j+1]*wB[j+1];
        }
        #pragma unroll
        for (int j = 0; j < 32; j += 2){
            float h0 = rdlane(h, j), h1 = rdlane(h, j+1);
            a1a += h0*uA[j];   a1b += h1*uA[j+1];
            a2a += h0*uB[j];   a2b += h1*uB[j+1];
        }
        float acc1 = a1a + a1b, acc2 = a2a + a2b;

        float sigA = fsigmoid(acc1);                 // low: sig(i), high: sig(f)
        float argB = (lane < 32) ? acc2 : 0.5f*acc2; // low: tanh(g), high: sig(o)
        float tt   = ftanh(argB);
        float actB = (lane < 32) ? tt : (0.5f + 0.5f*tt);
        float fsig = xshuf<32>(sigA, lane);
        float osig = xshuf<32>(actB, lane);
        c = fsig*c + sigA*actB;
        float hn = osig * ftanh(c);

        // ---- logistic + henon ----
        hn = 3.99f * hn * (1.f - hn);
        float x0 = rdlane(hn, 0), y0 = rdlane(hn, 1);
        float xnv = 1.f - 1.4f*x0*x0 + y0;
        float ynv = 0.3f * x0;

        // ---- quantum circuit: product-state init ----
        float ang[6];
        ang[0] = 0.5f*xnv; ang[1] = 0.5f*ynv;
        ang[2] = 0.5f*rdlane(hn, 2); ang[3] = 0.5f*rdlane(hn, 3);
        ang[4] = 0.5f*rdlane(hn, 4); ang[5] = 0.5f*rdlane(hn, 5);
        float ca[6], sa[6];
        #pragma unroll
        for (int j = 0; j < 6; j++){ ca[j] = __cosf(ang[j]); sa[j] = __sinf(ang[j]); }

        float fr[6], fi[6];
        #pragma unroll
        for (int i = 0; i < 6; i++){
            const int i1 = (i+1)%6, i2 = (i+2)%6;
            float cx=ca[i], sx=sa[i], cy=ca[i1], sy=sa[i1], cz=ca[i2], sz=sa[i2];
            float w0r = cy*cx, w0i = sy*sx;       // RY*RX|0>
            float w1r = sy*cx, w1i = -cy*sx;
            float q0r = cz*w0r + sz*w0i, q0i = cz*w0i - sz*w0r;   // * e^{-i az}
            float q1r = cz*w1r - sz*w1i, q1i = cz*w1i + sz*w1r;   // * e^{+i az}
            bool qb = (i==0)?qb0:(i==1)?qb1:(i==2)?qb2:(i==3)?qb3:(i==4)?qb4:qb5;
            fr[i] = qb ? q1r : q0r;
            fi[i] = qb ? q1i : q0i;
        }
        float t01r = fr[0]*fr[1] - fi[0]*fi[1], t01i = fr[0]*fi[1] + fi[0]*fr[1];
        float t23r = fr[2]*fr[3] - fi[2]*fi[3], t23i = fr[2]*fi[3] + fi[2]*fr[3];
        float t45r = fr[4]*fr[5] - fi[4]*fi[5], t45i = fr[4]*fi[5] + fi[4]*fr[5];
        float t03r = t01r*t23r - t01i*t23i,     t03i = t01r*t23i + t01i*t23r;
        float ar   = t03r*t45r - t03i*t45i,     ai   = t03r*t45i + t03i*t45r;

        // ---- entangling layers: RY as xor-exchange in relabeled basis ----
        #define GATE(L,Q) { \
            constexpr int MM = QM.M[L][Q]; \
            float br = xshuf<MM>(ar, lane), bi = xshuf<MM>(ai, lane); \
            float cg = cgv[(L)*6+(Q)], ss = ssin[(L)*6+(Q)]; \
            ar = cg*ar + ss*br; ai = cg*ai + ss*bi; }
        GATE(0,0) GATE(0,1) GATE(0,2) GATE(0,3) GATE(0,4) GATE(0,5)
        GATE(1,0) GATE(1,1) GATE(1,2) GATE(1,3) GATE(1,4) GATE(1,5)
        GATE(2,0) GATE(2,1) GATE(2,2) GATE(2,3) GATE(2,4) GATE(2,5)
        #undef GATE

        // ---- expvals: full Walsh-Hadamard butterfly, pick rows of Pi^-3 ----
        float wp = ar*ar + ai*ai;
        wp = wsgn[0]*wp + xshuf< 1>(wp, lane);
        wp = wsgn[1]*wp + xshuf< 2>(wp, lane);
        wp = wsgn[2]*wp + xshuf< 4>(wp, lane);
        wp = wsgn[3]*wp + xshuf< 8>(wp, lane);
        wp = wsgn[4]*wp + xshuf<16>(wp, lane);
        wp = wsgn[5]*wp + xshuf<32>(wp, lane);
        float ev0 = rdlane(wp, QM.R[0]), ev1 = rdlane(wp, QM.R[1]);
        float ev2 = rdlane(wp, QM.R[2]), ev3 = rdlane(wp, QM.R[3]);
        float ev4 = rdlane(wp, QM.R[4]), ev5 = rdlane(wp, QM.R[5]);

        float upd = bfcl + (wfcr[0]*ev0 + wfcr[1]*ev1)
                         + (wfcr[2]*ev2 + wfcr[3]*ev3)
                         + (wfcr[4]*ev4 + wfcr[5]*ev5);

        float hsel = hn;
        hsel = (lane == 0u) ? xnv : hsel;
        hsel = (lane == 1u) ? ynv : hsel;
        h = hsel + upd;
    }

    // ---- output: sigmoid(h . Wout + bout) ----
    float pv = (lane < 32) ? h*woutl : 0.f;
    #pragma unroll
    for (int off = 32; off; off >>= 1) pv += __shfl_xor(pv, off, 64);
    if (lane == 0) out[b] = fsigmoid(pv + boutv);
}

extern "C" void kernel_launch(void* const* d_in, const int* in_sizes, int n_in,
                              void* d_out, int out_size, void* d_ws, size_t ws_size,
                              hipStream_t stream)
{
    (void)in_sizes; (void)n_in; (void)out_size; (void)ws_size;
    const float* x    = (const float*)d_in[0];
    const float* w0   = (const float*)d_in[1];
    const float* b0   = (const float*)d_in[2];
    const float* w1   = (const float*)d_in[3];
    const float* b1   = (const float*)d_in[4];
    const float* w2   = (const float*)d_in[5];
    const float* b2   = (const float*)d_in[6];
    const float* Wih  = (const float*)d_in[7];
    const float* Whh  = (const float*)d_in[8];
    const float* bih  = (const float*)d_in[9];
    const float* bhh  = (const float*)d_in[10];
    const float* qw   = (const float*)d_in[11];
    const float* Wfc  = (const float*)d_in[12];
    const float* bfc  = (const float*)d_in[13];
    const float* Wout = (const float*)d_in[14];
    const float* bout = (const float*)d_in[15];
    float* out = (float*)d_out;

    float* t0 = (float*)d_ws;                              // (B,32,T) 32 MB
    float* t1 = t0 + (size_t)B_SIZE*HC*T_LEN;              // (B,32,T) 32 MB
    float* tS = t0;                                        // (T,B,32) reuses t0

    conv0_kernel<<<4096, 64, 0, stream>>>(x, w0, b0, t0);
    convm_kernel<false><<<4096, 64, 0, stream>>>(t0, w1, b1, t1);
    convm_kernel<true ><<<4096, 64, 0, stream>>>(t1, w2, b2, tS);
    scan_kernel<<<256, 256, 0, stream>>>(tS, Wih, Whh, bih, bhh, qw, Wfc, bfc, Wout, bout, out);
}